// Round 1
// baseline (237.098 us; speedup 1.0000x reference)
//
#include <hip/hip_runtime.h>

typedef __bf16 bf16_t;
typedef bf16_t bf16x8 __attribute__((ext_vector_type(8)));
typedef float f32x4 __attribute__((ext_vector_type(4)));
typedef unsigned short u16x8 __attribute__((ext_vector_type(8)));
typedef unsigned short u16x4 __attribute__((ext_vector_type(4)));

#define CD 768
#define NT 196
#define NB 128
#define T2 392

__device__ __forceinline__ unsigned short f2bf(float f){
  unsigned u = __float_as_uint(f);
  u += 0x7fffu + ((u >> 16) & 1u);
  return (unsigned short)(u >> 16);
}
__device__ __forceinline__ float bf2f(unsigned short h){
  return __uint_as_float(((unsigned)h) << 16);
}
__device__ __forceinline__ float wave_reduce(float v){
  #pragma unroll
  for (int o = 32; o > 0; o >>= 1) v += __shfl_down(v, o, 64);
  return v;
}

// Transpose W1/W2 into bf16 [n][k] so GEMM B-staging is coalesced along k.
__global__ void prep_wt(const float* __restrict__ W1, const float* __restrict__ W2,
                        unsigned short* __restrict__ W1t, unsigned short* __restrict__ W2t){
  int id = blockIdx.x*256 + threadIdx.x;
  if (id >= CD*CD) return;
  int n = id / CD, k = id - n*CD;
  W1t[id] = f2bf(W1[k*CD + n]);
  W2t[id] = f2bf(W2[k*CD + n]);
}

// u3[k] = W3[k,:]@w5a ; u4s[j] = (W4[j,:]+W4[392+j,:])@w5b ; c = b3@w5a + b4@w5b + b5
__global__ void prep_u(const float* __restrict__ W3, const float* __restrict__ W4,
                       const float* __restrict__ W5, const float* __restrict__ b3,
                       const float* __restrict__ b4, const float* __restrict__ b5,
                       float* __restrict__ u3, float* __restrict__ u4s, float* __restrict__ cbuf){
  int wid = (blockIdx.x*blockDim.x + threadIdx.x) >> 6;
  int lane = threadIdx.x & 63;
  const float* w5a = W5;
  const float* w5b = W5 + CD;
  float s = 0.f;
  if (wid < CD){
    const float* row = W3 + (size_t)wid*CD;
    for (int k = lane; k < CD; k += 64) s += row[k]*w5a[k];
    s = wave_reduce(s);
    if (lane == 0) u3[wid] = s;
  } else if (wid < CD + T2){
    int j = wid - CD;
    const float* r0 = W4 + (size_t)j*784;
    const float* r1 = W4 + (size_t)(j+T2)*784;
    for (int e = lane; e < 784; e += 64) s += (r0[e]+r1[e])*w5b[e];
    s = wave_reduce(s);
    if (lane == 0) u4s[j] = s;
  } else if (wid == CD + T2){
    for (int k = lane; k < CD; k += 64) s += b3[k]*w5a[k];
    for (int e = lane; e < 784; e += 64) s += b4[e]*w5b[e];
    s = wave_reduce(s);
    if (lane == 0) cbuf[0] = s + b5[0];
  }
}

// phi = relu((X@W + b)*g + be), bf16 output scattered into [B,392,768] at tok_off.
// 128x128 tile, BK=32, 4 waves (2x2), mfma_f32_16x16x32_bf16, XOR-swizzled LDS.
__global__ __launch_bounds__(256) void phi_gemm(
    const float* __restrict__ X, const unsigned short* __restrict__ Bt,
    const float* __restrict__ bias, const float* __restrict__ gam,
    const float* __restrict__ bet, unsigned short* __restrict__ phi, int tok_off)
{
  __shared__ unsigned short As[128*32];
  __shared__ unsigned short Bs[128*32];

  const int tid = threadIdx.x;
  const int lane = tid & 63;
  const int wid = tid >> 6;
  const int wr = wid >> 1, wc = wid & 1;
  const int bm = blockIdx.x, bn = blockIdx.y;

  f32x4 acc[4][4] = {};

  const int srow = tid >> 1;            // 0..127
  const int sseg = (tid & 1) << 4;      // 0 / 16 (elements)
  const int slot0 = sseg >> 3;          // 0 / 2 (16B slots)
  const int sw0 = ((slot0 ^ (srow & 3)) << 3);
  const int sw1 = (((slot0+1) ^ (srow & 3)) << 3);

  const float* xr = X + (size_t)(bm*128 + srow)*CD;
  const unsigned short* br = Bt + (size_t)(bn*128 + srow)*CD;
  const int kfsel = lane >> 4;          // 0..3: which 16B slot a frag read hits

  for (int kt = 0; kt < CD/32; ++kt){
    const int k0 = kt*32 + sseg;
    float4 f0 = *(const float4*)(xr + k0);
    float4 f1 = *(const float4*)(xr + k0 + 4);
    float4 f2 = *(const float4*)(xr + k0 + 8);
    float4 f3 = *(const float4*)(xr + k0 + 12);
    u16x8 a0 = { f2bf(f0.x), f2bf(f0.y), f2bf(f0.z), f2bf(f0.w),
                 f2bf(f1.x), f2bf(f1.y), f2bf(f1.z), f2bf(f1.w) };
    u16x8 a1 = { f2bf(f2.x), f2bf(f2.y), f2bf(f2.z), f2bf(f2.w),
                 f2bf(f3.x), f2bf(f3.y), f2bf(f3.z), f2bf(f3.w) };
    u16x8 b0 = *(const u16x8*)(br + k0);
    u16x8 b1 = *(const u16x8*)(br + k0 + 8);
    *(u16x8*)(&As[srow*32 + sw0]) = a0;
    *(u16x8*)(&As[srow*32 + sw1]) = a1;
    *(u16x8*)(&Bs[srow*32 + sw0]) = b0;
    *(u16x8*)(&Bs[srow*32 + sw1]) = b1;
    __syncthreads();

    bf16x8 af[4], bq[4];
    #pragma unroll
    for (int mi = 0; mi < 4; ++mi){
      int row = wr*64 + mi*16 + (lane & 15);
      af[mi] = *(const bf16x8*)(&As[row*32 + ((kfsel ^ (row & 3)) << 3)]);
    }
    #pragma unroll
    for (int ni = 0; ni < 4; ++ni){
      int col = wc*64 + ni*16 + (lane & 15);
      bq[ni] = *(const bf16x8*)(&Bs[col*32 + ((kfsel ^ (col & 3)) << 3)]);
    }
    #pragma unroll
    for (int mi = 0; mi < 4; ++mi)
      #pragma unroll
      for (int ni = 0; ni < 4; ++ni)
        acc[mi][ni] = __builtin_amdgcn_mfma_f32_16x16x32_bf16(af[mi], bq[ni], acc[mi][ni], 0, 0, 0);
    __syncthreads();
  }

  // epilogue: BN-affine + ReLU, store bf16 into phi[b*392 + tok_off + i][col]
  #pragma unroll
  for (int ni = 0; ni < 4; ++ni){
    int col = bn*128 + wc*64 + ni*16 + (lane & 15);
    float bi = bias[col], ga = gam[col], be = bet[col];
    #pragma unroll
    for (int mi = 0; mi < 4; ++mi){
      int r0 = bm*128 + wr*64 + mi*16 + ((lane >> 4) << 2);
      #pragma unroll
      for (int j = 0; j < 4; ++j){
        int r = r0 + j;
        int b = r / NT, i = r - b*NT;
        float v = (acc[mi][ni][j] + bi)*ga + be;
        v = fmaxf(v, 0.f);
        phi[(size_t)(b*T2 + tok_off + i)*CD + col] = f2bf(v);
      }
    }
  }
}

// t[b,d] = u3[d] + sum_j u4s[j]*phi[b,j,d]
__global__ __launch_bounds__(256) void comp_t(const unsigned short* __restrict__ phi,
                       const float* __restrict__ u3, const float* __restrict__ u4s,
                       float* __restrict__ t){
  __shared__ float su[T2];
  int b = blockIdx.x;
  int d = blockIdx.y*256 + threadIdx.x;
  for (int j = threadIdx.x; j < T2; j += 256) su[j] = u4s[j];
  __syncthreads();
  const unsigned short* p = phi + (size_t)b*T2*CD + d;
  float s = 0.f;
  #pragma unroll 8
  for (int j = 0; j < T2; ++j) s += su[j]*bf2f(p[(size_t)j*CD]);
  t[b*CD + d] = u3[d] + s;
}

// Wf[b*392+i] = phi[b,i,:]@t[b,:] + c   (one wave per row)
__global__ __launch_bounds__(256) void comp_w(const unsigned short* __restrict__ phi,
                       const float* __restrict__ t, const float* __restrict__ cbuf,
                       float* __restrict__ Wf){
  int gw = (blockIdx.x*256 + threadIdx.x) >> 6;
  int lane = threadIdx.x & 63;
  int b = gw / T2;
  const unsigned short* p = phi + (size_t)gw*CD;
  const float* tb = t + b*CD;
  float s = 0.f;
  #pragma unroll
  for (int it = 0; it < 3; ++it){
    int k = it*256 + lane*4;
    u16x4 u = *(const u16x4*)(p + k);
    float4 tv = *(const float4*)(tb + k);
    s += bf2f(u.x)*tv.x + bf2f(u.y)*tv.y + bf2f(u.z)*tv.z + bf2f(u.w)*tv.w;
  }
  s = wave_reduce(s);
  if (lane == 0) Wf[gw] = s + cbuf[0];
}

// out = x*Wx + y*Wy (float4 per thread)
__global__ __launch_bounds__(256) void comp_out(const float* __restrict__ x,
                         const float* __restrict__ y, const float* __restrict__ Wf,
                         float* __restrict__ out){
  int id = blockIdx.x*256 + threadIdx.x;     // one float4
  int tokv = id / 192;                       // b*196 + i
  int b = tokv / NT, i = tokv - b*NT;
  float wx = Wf[b*T2 + i];
  float wy = Wf[b*T2 + NT + i];
  float4 xv = ((const float4*)x)[id];
  float4 yv = ((const float4*)y)[id];
  float4 o;
  o.x = xv.x*wx + yv.x*wy;
  o.y = xv.y*wx + yv.y*wy;
  o.z = xv.z*wx + yv.z*wy;
  o.w = xv.w*wx + yv.w*wy;
  ((float4*)out)[id] = o;
}

extern "C" void kernel_launch(void* const* d_in, const int* in_sizes, int n_in,
                              void* d_out, int out_size, void* d_ws, size_t ws_size,
                              hipStream_t stream){
  const float* x  = (const float*)d_in[0];
  const float* y  = (const float*)d_in[1];
  const float* W1 = (const float*)d_in[2];
  const float* b1 = (const float*)d_in[3];
  const float* g1 = (const float*)d_in[4];
  const float* be1= (const float*)d_in[5];
  const float* W2 = (const float*)d_in[6];
  const float* b2 = (const float*)d_in[7];
  const float* g2 = (const float*)d_in[8];
  const float* be2= (const float*)d_in[9];
  const float* W3 = (const float*)d_in[10];
  const float* b3 = (const float*)d_in[11];
  const float* W4 = (const float*)d_in[12];
  const float* b4 = (const float*)d_in[13];
  const float* W5 = (const float*)d_in[14];
  const float* b5 = (const float*)d_in[15];
  float* out = (float*)d_out;

  unsigned short* W1t = (unsigned short*)d_ws;          // 768*768 bf16
  unsigned short* W2t = W1t + CD*CD;                    // 768*768 bf16
  unsigned short* phi = W2t + CD*CD;                    // 128*392*768 bf16
  float* u3   = (float*)(phi + (size_t)NB*T2*CD);       // 768
  float* u4s  = u3 + CD;                                // 392
  float* cbuf = u4s + T2;                               // 1 (+pad)
  float* t    = cbuf + 4;                               // 128*768
  float* Wf   = t + NB*CD;                              // 128*392

  prep_wt<<<(CD*CD + 255)/256, 256, 0, stream>>>(W1, W2, W1t, W2t);
  prep_u<<<(CD + T2 + 1 + 3)/4, 256, 0, stream>>>(W3, W4, W5, b3, b4, b5, u3, u4s, cbuf);

  dim3 gg(196, 6);
  phi_gemm<<<gg, 256, 0, stream>>>(x, W1t, b1, g1, be1, phi, 0);
  phi_gemm<<<gg, 256, 0, stream>>>(y, W2t, b2, g2, be2, phi, NT);

  comp_t<<<dim3(NB, 3), 256, 0, stream>>>(phi, u3, u4s, t);
  comp_w<<<(NB*T2)/4, 256, 0, stream>>>(phi, t, cbuf, Wf);
  comp_out<<<(NB*NT*CD/4)/256, 256, 0, stream>>>(x, y, Wf, out);
}